// Round 2
// baseline (2235.001 us; speedup 1.0000x reference)
//
#include <hip/hip_runtime.h>

#define NN 50000
#define NFEAT 128
#define NG 3
#define NE 600000

typedef unsigned int u32;
typedef unsigned short u16;
typedef __bf16 bf16x8 __attribute__((ext_vector_type(8)));
typedef float f32x4 __attribute__((ext_vector_type(4)));

__device__ __forceinline__ u16 f2bf(float f){
  u32 u = __float_as_uint(f);
  return (u16)((u + 0x7fffu + ((u >> 16) & 1u)) >> 16);   // RNE f32->bf16
}
__device__ __forceinline__ float bf2f(u32 s){
  return __uint_as_float((s & 0xffffu) << 16);
}
__device__ __forceinline__ u32 pack2(float a, float b){
  return (u32)f2bf(a) | ((u32)f2bf(b) << 16);
}
__device__ __forceinline__ float sigm(float x){ return 1.f / (1.f + __expf(-x)); }

// ---------------------------------------------------------------------------
// Weight prep: transpose+convert all weight matrices to bf16 Wt[c][k]
// WT layout (u16 units): fc1(3*16384) | c1 | c2 | d1 | d2 | fc2a | fc2b
// ---------------------------------------------------------------------------
__global__ void wprep_kernel(const float* fc1w, const float* wc1, const float* wc2,
                             const float* wd1, const float* wd2, const float* fc2w,
                             u16* WT){
  int idx = blockIdx.x * 256 + threadIdx.x;
  if (idx >= 147456) return;
  float v;
  if (idx < 49152){
    int g = idx / 16384, r = idx % 16384; int o = r / 128, f = r % 128;
    v = fc1w[g * 16384 + f * 128 + o];
  } else if (idx < 114688){
    int m = (idx - 49152) / 16384, r = (idx - 49152) % 16384;
    int o = r / 128, f = r % 128;
    const float* w = (m == 0) ? wc1 : (m == 1) ? wc2 : (m == 2) ? wd1 : wd2;
    v = w[f * 128 + o];
  } else {
    int r = idx - 114688; int half = r / 16384; r %= 16384;
    int o = r / 128, f = r % 128;
    v = fc2w[(half * 128 + f) * 128 + o];
  }
  WT[idx] = f2bf(v);
}

// ---------------------------------------------------------------------------
// CSR build
// ---------------------------------------------------------------------------
__global__ void deg_kernel(const int* ei, int* deg){
  int t = blockIdx.x * 256 + threadIdx.x;
  if (t >= NG * NE) return;
  int g = t / NE, e = t - g * NE;
  int dst = ei[(size_t)g * 2 * NE + NE + e];
  atomicAdd(deg + (size_t)g * NN + dst, 1);
}

__global__ __launch_bounds__(1024) void scan_kernel(const int* deg, int* rowptr, float* dinv){
  const int g = blockIdx.x;
  const int* d = deg + (size_t)g * NN;
  int* rp = rowptr + g * (NN + 1);
  float* di = dinv + (size_t)g * NN;
  __shared__ int s[1024];
  __shared__ int carry;
  if (threadIdx.x == 0) carry = 0;
  __syncthreads();
  for (int base = 0; base <= NN; base += 1024){
    int idx = base + threadIdx.x;
    int v = (idx < NN) ? d[idx] : 0;
    if (idx < NN) di[idx] = rsqrtf((float)(v + 1));   // deg includes self-loop
    s[threadIdx.x] = v;
    __syncthreads();
    for (int off = 1; off < 1024; off <<= 1){
      int x = (threadIdx.x >= off) ? s[threadIdx.x - off] : 0;
      __syncthreads();
      s[threadIdx.x] += x;
      __syncthreads();
    }
    int incl = s[threadIdx.x];
    int run = carry;
    if (idx <= NN) rp[idx] = run + incl - v;   // exclusive
    __syncthreads();
    if (threadIdx.x == 1023) carry = run + s[1023];
    __syncthreads();
  }
}

__global__ void fill_kernel(const int* ei, const int* rowptr, int* cursor, int* colbuf){
  int t = blockIdx.x * 256 + threadIdx.x;
  if (t >= NG * NE) return;
  int g = t / NE, e = t - g * NE;
  int src = ei[(size_t)g * 2 * NE + e];
  int dst = ei[(size_t)g * 2 * NE + NE + e];
  int pos = atomicAdd(cursor + (size_t)g * NN + dst, 1);
  colbuf[(size_t)g * NE + rowptr[g * (NN + 1) + dst] + pos] = src;
}

// ---------------------------------------------------------------------------
// GEMM: Out[g][n][c] = sum_k A[g][n][k] * W[k][c] (+bias), bf16 out, MFMA bf16.
// Orientation: MFMA-A = Wt (m=feature), MFMA-B = activations (n=node), so
// lane holds 4 consecutive features of one node -> contiguous 8B C-stores.
// MODE 0: A bf16 per-graph. MODE 1: A f32 (x). MODE 2: A = 0.5*(A2sum - enc[g]).
// MODE 3: two passes (own2@Wa + oth2@Wb), K=256 via accumulation.
// LDS tiles swizzled: byte ^= (row&7)<<4 (16B chunk permute -> conflict-free).
// ---------------------------------------------------------------------------
template<int MODE>
__global__ __launch_bounds__(256, 2) void gemm_kernel(
    const void* Ap, const void* Ap2, const u16* W, const u16* W2,
    const float* bias, u16* Out, int wPerG, int biasPerG, int hasBias)
{
  __shared__ __align__(16) unsigned char sA[128 * 256];
  __shared__ __align__(16) unsigned char sW[128 * 256];
  const int tid = threadIdx.x;
  const int g = blockIdx.y;
  const int nb = blockIdx.x * 128;
  const int lane = tid & 63, wv = tid >> 6;
  const int wm = (wv & 1) * 64, wn = (wv >> 1) * 64;
  const int l15 = lane & 15, lh = lane >> 4;
  f32x4 acc[4][4] = {};
  constexpr int passes = (MODE == 3) ? 2 : 1;
  for (int p = 0; p < passes; p++){
    if (p) __syncthreads();
    { // stage W tile [feat][128] bf16 (pre-transposed), swizzled
      const u16* wsrc = (p ? W2 : W) + (wPerG ? g * 16384 : 0);
      const uint4* w4 = (const uint4*)wsrc;
      for (int i = tid; i < 2048; i += 256){
        int r = i >> 4, c = i & 15;
        uint4 v = w4[i];
        *(uint4*)(sW + r * 256 + ((c * 16) ^ ((r & 7) << 4))) = v;
      }
    }
    if (MODE == 1){
      const float* xp = (const float*)Ap + (size_t)g * NN * NFEAT;
      for (int i = tid; i < 2048; i += 256){
        int r = i >> 4, c = i & 15; int node = nb + r;
        uint4 o = {0, 0, 0, 0};
        if (node < NN){
          const float* row = xp + (size_t)node * NFEAT + c * 8;
          float4 a4 = *(const float4*)row;
          float4 b4 = *(const float4*)(row + 4);
          o.x = pack2(a4.x, a4.y); o.y = pack2(a4.z, a4.w);
          o.z = pack2(b4.x, b4.y); o.w = pack2(b4.z, b4.w);
        }
        *(uint4*)(sA + r * 256 + ((c * 16) ^ ((r & 7) << 4))) = o;
      }
    } else if (MODE == 2){
      const uint4* pe = (const uint4*)((const u16*)Ap + (size_t)g * NN * NFEAT);
      const uint4* ps = (const uint4*)Ap2;   // enc_sum, shared
      for (int i = tid; i < 2048; i += 256){
        int r = i >> 4, c = i & 15; int node = nb + r;
        uint4 o = {0, 0, 0, 0};
        if (node < NN){
          uint4 va = pe[(size_t)node * 16 + c];
          uint4 vb = ps[(size_t)node * 16 + c];
          o.x = pack2(0.5f * (bf2f(vb.x) - bf2f(va.x)), 0.5f * (bf2f(vb.x >> 16) - bf2f(va.x >> 16)));
          o.y = pack2(0.5f * (bf2f(vb.y) - bf2f(va.y)), 0.5f * (bf2f(vb.y >> 16) - bf2f(va.y >> 16)));
          o.z = pack2(0.5f * (bf2f(vb.z) - bf2f(va.z)), 0.5f * (bf2f(vb.z >> 16) - bf2f(va.z >> 16)));
          o.w = pack2(0.5f * (bf2f(vb.w) - bf2f(va.w)), 0.5f * (bf2f(vb.w >> 16) - bf2f(va.w >> 16)));
        }
        *(uint4*)(sA + r * 256 + ((c * 16) ^ ((r & 7) << 4))) = o;
      }
    } else {
      const u16* asrc = (const u16*)(p ? Ap2 : Ap) + (size_t)g * NN * NFEAT;
      const uint4* a4 = (const uint4*)asrc;
      for (int i = tid; i < 2048; i += 256){
        int r = i >> 4, c = i & 15; int node = nb + r;
        uint4 v = {0, 0, 0, 0};
        if (node < NN) v = a4[(size_t)node * 16 + c];
        *(uint4*)(sA + r * 256 + ((c * 16) ^ ((r & 7) << 4))) = v;
      }
    }
    __syncthreads();
    #pragma unroll
    for (int k0 = 0; k0 < 128; k0 += 32){
      const int kb = 2 * (k0 + lh * 8);
      bf16x8 af[4], bfr[4];
      #pragma unroll
      for (int t = 0; t < 4; t++){
        int rm = wm + t * 16 + l15;
        af[t] = *reinterpret_cast<const bf16x8*>(sW + rm * 256 + (kb ^ ((rm & 7) << 4)));
        int rn = wn + t * 16 + l15;
        bfr[t] = *reinterpret_cast<const bf16x8*>(sA + rn * 256 + (kb ^ ((rn & 7) << 4)));
      }
      #pragma unroll
      for (int mi = 0; mi < 4; mi++)
        #pragma unroll
        for (int ni = 0; ni < 4; ni++)
          acc[mi][ni] = __builtin_amdgcn_mfma_f32_16x16x32_bf16(af[mi], bfr[ni], acc[mi][ni], 0, 0, 0);
    }
  }
  u16* outg = Out + (size_t)g * NN * NFEAT;
  #pragma unroll
  for (int mi = 0; mi < 4; mi++){
    int mbase = wm + mi * 16 + lh * 4;
    f32x4 bv = {};
    if (hasBias) bv = *reinterpret_cast<const f32x4*>(bias + (biasPerG ? g * NFEAT : 0) + mbase);
    #pragma unroll
    for (int ni = 0; ni < 4; ni++){
      int node = nb + wn + ni * 16 + l15;
      if (node < NN){
        f32x4 v = acc[mi][ni];
        ushort4 o;
        o.x = f2bf(v.x + bv.x); o.y = f2bf(v.y + bv.y);
        o.z = f2bf(v.z + bv.z); o.w = f2bf(v.w + bv.w);
        *reinterpret_cast<ushort4*>(outg + (size_t)node * NFEAT + mbase) = o;
      }
    }
  }
}

// ---------------------------------------------------------------------------
// GCN aggregation: out[v] = dinv[v]*(sum_e dinv[src]*h[src] + dinv[v]*h[v]) + b
// Wave per node, lane = 2 features. Optional fused sum((Ref-out)^2) per graph.
// ---------------------------------------------------------------------------
template<bool SQ>
__global__ __launch_bounds__(256) void agg_kernel(
    const u16* H, u16* Outp, const float* bias, const float* dinv,
    const int* rowptr, const int* colidx, const u16* Ref, float* sqslot)
{
  __shared__ float red[256];
  const int g = blockIdx.y;
  const int v = blockIdx.x * 4 + (threadIdx.x >> 6);
  const int l = threadIdx.x & 63;
  const u32* h = (const u32*)(H + (size_t)g * NN * NFEAT);
  const float* dv = dinv + (size_t)g * NN;
  const int* rp = rowptr + g * (NN + 1);
  const int* ci = colidx + (size_t)g * NE;
  float ax = 0.f, ay = 0.f;
  const int e0 = rp[v], e1 = rp[v + 1];
  int e = e0;
  for (; e + 1 < e1; e += 2){
    int s0 = ci[e], s1 = ci[e + 1];
    float w0 = dv[s0], w1 = dv[s1];
    u32 h0 = h[(size_t)s0 * 64 + l], h1 = h[(size_t)s1 * 64 + l];
    ax += w0 * bf2f(h0) + w1 * bf2f(h1);
    ay += w0 * bf2f(h0 >> 16) + w1 * bf2f(h1 >> 16);
  }
  if (e < e1){
    int s0 = ci[e]; float w0 = dv[s0];
    u32 h0 = h[(size_t)s0 * 64 + l];
    ax += w0 * bf2f(h0); ay += w0 * bf2f(h0 >> 16);
  }
  const float dvv = dv[v];
  u32 hs = h[(size_t)v * 64 + l];
  ax = (ax + dvv * bf2f(hs)) * dvv;
  ay = (ay + dvv * bf2f(hs >> 16)) * dvv;
  const float2 b2 = *(const float2*)(bias + 2 * l);
  ax += b2.x; ay += b2.y;
  ((u32*)(Outp + (size_t)g * NN * NFEAT))[(size_t)v * 64 + l] = pack2(ax, ay);
  if (SQ){
    u32 rv = ((const u32*)(Ref + (size_t)g * NN * NFEAT))[(size_t)v * 64 + l];
    float dx = bf2f(rv) - ax, dy = bf2f(rv >> 16) - ay;
    red[threadIdx.x] = dx * dx + dy * dy;
    __syncthreads();
    for (int s2 = 128; s2 > 0; s2 >>= 1){
      if (threadIdx.x < s2) red[threadIdx.x] += red[threadIdx.x + s2];
      __syncthreads();
    }
    if (threadIdx.x == 0) atomicAdd(sqslot + g, red[0]);
  }
}

// ---------------------------------------------------------------------------
// enc_sum (bf16), used_feat = elu(enc_sum/3) -> d_out, colsum partials
// ---------------------------------------------------------------------------
__global__ __launch_bounds__(256) void encsum_kernel(
    const u16* Enc, u16* EncSum, float* outUsed, float* colsum)
{
  const int fp = threadIdx.x & 63, sub = threadIdx.x >> 6;
  const u32* e0 = (const u32*)Enc;
  const u32* e1 = e0 + (size_t)NN * 64;
  const u32* e2 = e1 + (size_t)NN * 64;
  u32* es = (u32*)EncSum;
  float cs[6] = {0, 0, 0, 0, 0, 0};
  for (int v = blockIdx.x * 4 + sub; v < NN; v += gridDim.x * 4){
    size_t idx = (size_t)v * 64 + fp;
    u32 a = e0[idx], b = e1[idx], c = e2[idx];
    float axv = bf2f(a), ayv = bf2f(a >> 16);
    float bxv = bf2f(b), byv = bf2f(b >> 16);
    float cxv = bf2f(c), cyv = bf2f(c >> 16);
    cs[0] += axv; cs[1] += ayv; cs[2] += bxv; cs[3] += byv; cs[4] += cxv; cs[5] += cyv;
    float sx = axv + bxv + cxv, sy = ayv + byv + cyv;
    es[idx] = pack2(sx, sy);
    float ux = sx * (1.f / 3.f), uy = sy * (1.f / 3.f);
    float2 o;
    o.x = ux > 0.f ? ux : expm1f(ux);
    o.y = uy > 0.f ? uy : expm1f(uy);
    *(float2*)(outUsed + (size_t)v * NFEAT + 2 * fp) = o;
  }
  __shared__ float red[256];
  #pragma unroll
  for (int q = 0; q < 6; q++){
    red[threadIdx.x] = cs[q];
    __syncthreads();
    if (sub == 0){
      float s = red[fp] + red[64 + fp] + red[128 + fp] + red[192 + fp];
      atomicAdd(&colsum[(q >> 1) * NFEAT + 2 * fp + (q & 1)], s);
    }
    __syncthreads();
  }
}

// global_vec = sigmoid(colsum/N); u[i] = att_w[i] @ global_vec[i]
__global__ void gvecu_kernel(const float* colsum, const float* att, float* u){
  __shared__ float gv[3 * 128];
  const int t = threadIdx.x;   // 128 threads
  for (int g = 0; g < 3; g++) gv[g * 128 + t] = sigm(colsum[g * 128 + t] * (1.f / 50000.f));
  __syncthreads();
  for (int i = 0; i < 3; i++){
    float s = 0.f;
    for (int e = 0; e < 128; e++)
      s += att[(size_t)i * 16384 + (size_t)t * 128 + e] * gv[i * 128 + e];
    u[i * 128 + t] = s;
  }
}

// fuse_feat = sigmoid(mean_g each_fin) -> d_out; pairwise sqdiffs -> slots[6..8]
__global__ __launch_bounds__(256) void fuse_kernel(const u16* EF, float* outFuse, float* slots){
  const int fp = threadIdx.x & 63, sub = threadIdx.x >> 6;
  const u32* e0 = (const u32*)EF;
  const u32* e1 = e0 + (size_t)NN * 64;
  const u32* e2 = e1 + (size_t)NN * 64;
  float s01 = 0, s02 = 0, s12 = 0;
  for (int v = blockIdx.x * 4 + sub; v < NN; v += gridDim.x * 4){
    size_t idx = (size_t)v * 64 + fp;
    u32 a = e0[idx], b = e1[idx], c = e2[idx];
    float axv = bf2f(a), ayv = bf2f(a >> 16), bxv = bf2f(b), byv = bf2f(b >> 16);
    float cxv = bf2f(c), cyv = bf2f(c >> 16);
    float2 o;
    o.x = sigm((axv + bxv + cxv) * (1.f / 3.f));
    o.y = sigm((ayv + byv + cyv) * (1.f / 3.f));
    *(float2*)(outFuse + (size_t)v * NFEAT + 2 * fp) = o;
    float dx, dy;
    dx = axv - bxv; dy = ayv - byv; s01 += dx * dx + dy * dy;
    dx = axv - cxv; dy = ayv - cyv; s02 += dx * dx + dy * dy;
    dx = bxv - cxv; dy = byv - cyv; s12 += dx * dx + dy * dy;
  }
  __shared__ float red[256];
  float vals[3] = {s01, s02, s12};
  #pragma unroll
  for (int q = 0; q < 3; q++){
    red[threadIdx.x] = vals[q];
    __syncthreads();
    for (int s2 = 128; s2 > 0; s2 >>= 1){
      if (threadIdx.x < s2) red[threadIdx.x] += red[threadIdx.x + s2];
      __syncthreads();
    }
    if (threadIdx.x == 0) atomicAdd(slots + 6 + q, red[0]);
    __syncthreads();
  }
}

// comp_re[n][i*3+j] = S[i,j,n] / sum_j S[i,j,n],  S = sigmoid(enc[j,n].u[i])
__global__ __launch_bounds__(256) void comp_kernel(const u16* Enc, const float* u, float* outC){
  __shared__ float su[384];
  for (int i = threadIdx.x; i < 384; i += 256) su[i] = u[i];
  __syncthreads();
  const int v = blockIdx.x * 4 + (threadIdx.x >> 6);
  const int l = threadIdx.x & 63;
  const u32* e = (const u32*)Enc;
  float ex[3], ey[3];
  #pragma unroll
  for (int j = 0; j < 3; j++){
    u32 t = e[((size_t)j * NN + v) * 64 + l];
    ex[j] = bf2f(t); ey[j] = bf2f(t >> 16);
  }
  float p[9];
  #pragma unroll
  for (int i = 0; i < 3; i++){
    float uxi = su[i * 128 + 2 * l], uyi = su[i * 128 + 2 * l + 1];
    #pragma unroll
    for (int j = 0; j < 3; j++)
      p[i * 3 + j] = ex[j] * uxi + ey[j] * uyi;
  }
  #pragma unroll
  for (int q = 0; q < 9; q++){
    float s = p[q];
    #pragma unroll
    for (int off = 1; off < 64; off <<= 1) s += __shfl_xor(s, off, 64);
    p[q] = s;
  }
  if (l < 9){
    float sg[9];
    #pragma unroll
    for (int q = 0; q < 9; q++) sg[q] = sigm(p[q]);
    float d0 = sg[0] + sg[1] + sg[2], d1 = sg[3] + sg[4] + sg[5], d2 = sg[6] + sg[7] + sg[8];
    float num = sg[0];
    if (l == 1) num = sg[1]; if (l == 2) num = sg[2]; if (l == 3) num = sg[3];
    if (l == 4) num = sg[4]; if (l == 5) num = sg[5]; if (l == 6) num = sg[6];
    if (l == 7) num = sg[7]; if (l == 8) num = sg[8];
    float den = (l < 3) ? d0 : (l < 6) ? d1 : d2;
    outC[(size_t)v * 9 + l] = num / den;
  }
}

// obf1/obf0 final assembly
__global__ void final_kernel(const float* slots, float* out){
  if (threadIdx.x == 0){
    float obf1 = 0.f;
    for (int g = 0; g < 3; g++)
      obf1 += 0.5f * (sqrtf(slots[3 + g]) + sqrtf(slots[g]));
    float obf0 = 2.f * (sqrtf(slots[6]) + sqrtf(slots[7]) + sqrtf(slots[8]));
    out[13250000] = obf1;
    out[13250001] = obf0;
  }
}

// ---------------------------------------------------------------------------
extern "C" void kernel_launch(void* const* d_in, const int* in_sizes, int n_in,
                              void* d_out, int out_size, void* d_ws, size_t ws_size,
                              hipStream_t stream)
{
  (void)in_sizes; (void)n_in; (void)out_size;
  const float* x    = (const float*)d_in[0];
  const float* fc1w = (const float*)d_in[1];
  const float* fc1b = (const float*)d_in[2];
  const float* wc1  = (const float*)d_in[3];
  const float* bc1  = (const float*)d_in[4];
  const float* wc2  = (const float*)d_in[5];
  const float* bc2  = (const float*)d_in[6];
  const float* wd1  = (const float*)d_in[7];
  const float* bd1  = (const float*)d_in[8];
  const float* wd2  = (const float*)d_in[9];
  const float* bd2  = (const float*)d_in[10];
  const float* fc2w = (const float*)d_in[11];
  const float* fc2b = (const float*)d_in[12];
  const float* attw = (const float*)d_in[13];
  const int*   ei   = (const int*)d_in[14];
  float* out = (float*)d_out;
  char* ws = (char*)d_ws;

  constexpr size_t BUFB = (size_t)NG * NN * NFEAT * 2;   // 38,400,000 B per act buffer
  u16* WT   = (u16*)(ws + 0);
  u16* buf0 = (u16*)(ws + 327680);
  u16* buf1 = (u16*)(ws + 327680 + 1 * BUFB);
  u16* buf2 = (u16*)(ws + 327680 + 2 * BUFB);
  u16* buf3 = (u16*)(ws + 327680 + 3 * BUFB);
  u16* buf4 = (u16*)(ws + 327680 + 4 * BUFB);
  u16* buf5 = (u16*)(ws + 327680 + 5 * BUFB);
  size_t off = 327680 + 6 * BUFB;
  u16* encsum = (u16*)(ws + off); off += (size_t)NN * NFEAT * 2;
  float* dinv = (float*)(ws + off); off += (size_t)NG * NN * 4;
  int* rowptr = (int*)(ws + off); off += 600064;
  int* colbuf = (int*)(ws + off); off += (size_t)NG * NE * 4;
  size_t zero_off = off;
  int* deg     = (int*)(ws + off); off += (size_t)NG * NN * 4;
  int* cursor  = (int*)(ws + off); off += (size_t)NG * NN * 4;
  float* colsum = (float*)(ws + off); off += 1536;
  float* slots  = (float*)(ws + off); off += 64;
  size_t zero_bytes = off - zero_off;
  float* uvec = (float*)(ws + off); off += 1536;
  if (ws_size < off) return;   // workspace too small: fail loudly without OOB writes

  hipMemsetAsync(ws + zero_off, 0, zero_bytes, stream);

  wprep_kernel<<<576, 256, 0, stream>>>(fc1w, wc1, wc2, wd1, wd2, fc2w, WT);
  deg_kernel<<<7032, 256, 0, stream>>>(ei, deg);
  scan_kernel<<<NG, 1024, 0, stream>>>(deg, rowptr, dinv);
  fill_kernel<<<7032, 256, 0, stream>>>(ei, rowptr, cursor, colbuf);

  const u16* WT_fc1 = WT;
  const u16* WT_c1  = WT + 49152;
  const u16* WT_c2  = WT + 65536;
  const u16* WT_d1  = WT + 81920;
  const u16* WT_d2  = WT + 98304;
  const u16* WT_f2a = WT + 114688;
  const u16* WT_f2b = WT + 131072;
  dim3 gg(391, NG), ag(12500, NG);

  // pre_feat = x @ fc1_w + fc1_b                      -> buf0
  gemm_kernel<1><<<gg, 256, 0, stream>>>(x, nullptr, WT_fc1, nullptr, fc1b, buf0, 1, 1, 1);
  // conv1_f = GCN(pre_feat, wc1, bc1)                 -> buf1
  gemm_kernel<0><<<gg, 256, 0, stream>>>(buf0, nullptr, WT_c1, nullptr, nullptr, buf3, 0, 0, 0);
  agg_kernel<false><<<ag, 256, 0, stream>>>(buf3, buf1, bc1, dinv, rowptr, colbuf, nullptr, nullptr);
  // enc = GCN(conv1_f, wc2, bc2)                      -> buf2
  gemm_kernel<0><<<gg, 256, 0, stream>>>(buf1, nullptr, WT_c2, nullptr, nullptr, buf3, 0, 0, 0);
  agg_kernel<false><<<ag, 256, 0, stream>>>(buf3, buf2, bc2, dinv, rowptr, colbuf, nullptr, nullptr);
  // enc_sum / used_feat / colsum ; global_vec -> u
  encsum_kernel<<<256, 256, 0, stream>>>(buf2, encsum, out + 6400000, colsum);
  gvecu_kernel<<<1, 128, 0, stream>>>(colsum, attw, uvec);
  // own1 = GCN(enc, wd1, bd1)  + sq(conv1_f-own1)     -> buf4, slots[0..2]
  gemm_kernel<0><<<gg, 256, 0, stream>>>(buf2, nullptr, WT_d1, nullptr, nullptr, buf3, 0, 0, 0);
  agg_kernel<true><<<ag, 256, 0, stream>>>(buf3, buf4, bd1, dinv, rowptr, colbuf, buf1, slots + 0);
  // own2 = GCN(own1, wd2, bd2) + sq(pre_feat-own2)    -> buf5, slots[3..5]
  gemm_kernel<0><<<gg, 256, 0, stream>>>(buf4, nullptr, WT_d2, nullptr, nullptr, buf3, 0, 0, 0);
  agg_kernel<true><<<ag, 256, 0, stream>>>(buf3, buf5, bd2, dinv, rowptr, colbuf, buf0, slots + 3);
  // oth1 = GCN((enc_sum-enc)/2, wd1, bd1)             -> buf1 (conv1_f dead)
  gemm_kernel<2><<<gg, 256, 0, stream>>>(buf2, encsum, WT_d1, nullptr, nullptr, buf3, 0, 0, 0);
  agg_kernel<false><<<ag, 256, 0, stream>>>(buf3, buf1, bd1, dinv, rowptr, colbuf, nullptr, nullptr);
  // oth2 = GCN(oth1, wd2, bd2)                        -> buf4 (own1 dead)
  gemm_kernel<0><<<gg, 256, 0, stream>>>(buf1, nullptr, WT_d2, nullptr, nullptr, buf3, 0, 0, 0);
  agg_kernel<false><<<ag, 256, 0, stream>>>(buf3, buf4, bd2, dinv, rowptr, colbuf, nullptr, nullptr);
  // each_fin = [own2|oth2] @ fc2_w + fc2_b            -> buf0 (pre_feat dead)
  gemm_kernel<3><<<gg, 256, 0, stream>>>(buf5, buf4, WT_f2a, WT_f2b, fc2b, buf0, 0, 0, 1);
  // fuse_feat + obf0 pair sums
  fuse_kernel<<<256, 256, 0, stream>>>(buf0, out, slots);
  // comp_re
  comp_kernel<<<12500, 256, 0, stream>>>(buf2, uvec, out + 12800000);
  final_kernel<<<1, 64, 0, stream>>>(slots, out);
}

// Round 5
// 2078.292 us; speedup vs baseline: 1.0754x; 1.0754x over previous
//
#include <hip/hip_runtime.h>

#define NN 50000
#define NFEAT 128
#define NG 3
#define NE 600000

typedef unsigned int u32;
typedef unsigned short u16;
typedef __bf16 bf16x8 __attribute__((ext_vector_type(8)));
typedef float f32x4 __attribute__((ext_vector_type(4)));

__device__ __forceinline__ u16 f2bf(float f){
  u32 u = __float_as_uint(f);
  return (u16)((u + 0x7fffu + ((u >> 16) & 1u)) >> 16);   // RNE f32->bf16
}
__device__ __forceinline__ float bf2f(u32 s){
  return __uint_as_float((s & 0xffffu) << 16);
}
__device__ __forceinline__ u32 pack2(float a, float b){
  return (u32)f2bf(a) | ((u32)f2bf(b) << 16);
}
__device__ __forceinline__ float sigm(float x){ return 1.f / (1.f + __expf(-x)); }

// ---------------------------------------------------------------------------
// Weight prep: transpose+convert all weight matrices to bf16 Wt[c][k]
// ---------------------------------------------------------------------------
__global__ void wprep_kernel(const float* fc1w, const float* wc1, const float* wc2,
                             const float* wd1, const float* wd2, const float* fc2w,
                             u16* WT){
  int idx = blockIdx.x * 256 + threadIdx.x;
  if (idx >= 147456) return;
  float v;
  if (idx < 49152){
    int g = idx / 16384, r = idx % 16384; int o = r / 128, f = r % 128;
    v = fc1w[g * 16384 + f * 128 + o];
  } else if (idx < 114688){
    int m = (idx - 49152) / 16384, r = (idx - 49152) % 16384;
    int o = r / 128, f = r % 128;
    const float* w = (m == 0) ? wc1 : (m == 1) ? wc2 : (m == 2) ? wd1 : wd2;
    v = w[f * 128 + o];
  } else {
    int r = idx - 114688; int half = r / 16384; r %= 16384;
    int o = r / 128, f = r % 128;
    v = fc2w[(half * 128 + f) * 128 + o];
  }
  WT[idx] = f2bf(v);
}

// ---------------------------------------------------------------------------
// CSR build
// ---------------------------------------------------------------------------
__global__ void deg_kernel(const int* ei, int* deg){
  int t = blockIdx.x * 256 + threadIdx.x;
  if (t >= NG * NE) return;
  int g = t / NE, e = t - g * NE;
  int dst = ei[(size_t)g * 2 * NE + NE + e];
  atomicAdd(deg + (size_t)g * NN + dst, 1);
}

__global__ __launch_bounds__(1024) void scan_kernel(const int* deg, int* rowptr, float* dinv){
  const int g = blockIdx.x;
  const int* d = deg + (size_t)g * NN;
  int* rp = rowptr + g * (NN + 1);
  float* di = dinv + (size_t)g * NN;
  __shared__ int s[1024];
  __shared__ int carry;
  if (threadIdx.x == 0) carry = 0;
  __syncthreads();
  for (int base = 0; base <= NN; base += 1024){
    int idx = base + threadIdx.x;
    int v = (idx < NN) ? d[idx] : 0;
    if (idx < NN) di[idx] = rsqrtf((float)(v + 1));   // deg includes self-loop
    s[threadIdx.x] = v;
    __syncthreads();
    for (int off = 1; off < 1024; off <<= 1){
      int x = (threadIdx.x >= off) ? s[threadIdx.x - off] : 0;
      __syncthreads();
      s[threadIdx.x] += x;
      __syncthreads();
    }
    int incl = s[threadIdx.x];
    int run = carry;
    if (idx <= NN) rp[idx] = run + incl - v;   // exclusive
    __syncthreads();
    if (threadIdx.x == 1023) carry = run + s[1023];
    __syncthreads();
  }
}

__global__ void fill_kernel(const int* ei, const int* rowptr, int* cursor, int* colbuf){
  int t = blockIdx.x * 256 + threadIdx.x;
  if (t >= NG * NE) return;
  int g = t / NE, e = t - g * NE;
  int src = ei[(size_t)g * 2 * NE + e];
  int dst = ei[(size_t)g * 2 * NE + NE + e];
  int pos = atomicAdd(cursor + (size_t)g * NN + dst, 1);
  colbuf[(size_t)g * NE + rowptr[g * (NN + 1) + dst] + pos] = src;
}

// ---------------------------------------------------------------------------
// GEMM: Out[g][n][c] = (sum_k A[g][n][k] * W[k][c] (+bias)) * (scale?dinv[n]:1)
// MFMA-A = Wt (m=feature), MFMA-B = activations (n=node).
// scale != nullptr => pre-scale rows by dinv (producer of agg inputs).
// ---------------------------------------------------------------------------
template<int MODE>
__global__ __launch_bounds__(256, 2) void gemm_kernel(
    const void* Ap, const void* Ap2, const u16* W, const u16* W2,
    const float* bias, u16* Out, const float* scale,
    int wPerG, int biasPerG, int hasBias)
{
  __shared__ __align__(16) unsigned char sA[128 * 256];
  __shared__ __align__(16) unsigned char sW[128 * 256];
  const int tid = threadIdx.x;
  const int g = blockIdx.y;
  const int nb = blockIdx.x * 128;
  const int lane = tid & 63, wv = tid >> 6;
  const int wm = (wv & 1) * 64, wn = (wv >> 1) * 64;
  const int l15 = lane & 15, lh = lane >> 4;
  f32x4 acc[4][4] = {};
  constexpr int passes = (MODE == 3) ? 2 : 1;
  for (int p = 0; p < passes; p++){
    if (p) __syncthreads();
    { // stage W tile [feat][128] bf16 (pre-transposed), swizzled
      const u16* wsrc = (p ? W2 : W) + (wPerG ? g * 16384 : 0);
      const uint4* w4 = (const uint4*)wsrc;
      for (int i = tid; i < 2048; i += 256){
        int r = i >> 4, c = i & 15;
        uint4 v = w4[i];
        *(uint4*)(sW + r * 256 + ((c * 16) ^ ((r & 7) << 4))) = v;
      }
    }
    if (MODE == 1){
      const float* xp = (const float*)Ap + (size_t)g * NN * NFEAT;
      for (int i = tid; i < 2048; i += 256){
        int r = i >> 4, c = i & 15; int node = nb + r;
        uint4 o = {0, 0, 0, 0};
        if (node < NN){
          const float* row = xp + (size_t)node * NFEAT + c * 8;
          float4 a4 = *(const float4*)row;
          float4 b4 = *(const float4*)(row + 4);
          o.x = pack2(a4.x, a4.y); o.y = pack2(a4.z, a4.w);
          o.z = pack2(b4.x, b4.y); o.w = pack2(b4.z, b4.w);
        }
        *(uint4*)(sA + r * 256 + ((c * 16) ^ ((r & 7) << 4))) = o;
      }
    } else if (MODE == 2){
      const uint4* pe = (const uint4*)((const u16*)Ap + (size_t)g * NN * NFEAT);
      const uint4* ps = (const uint4*)Ap2;   // enc_sum, shared
      for (int i = tid; i < 2048; i += 256){
        int r = i >> 4, c = i & 15; int node = nb + r;
        uint4 o = {0, 0, 0, 0};
        if (node < NN){
          uint4 va = pe[(size_t)node * 16 + c];
          uint4 vb = ps[(size_t)node * 16 + c];
          o.x = pack2(0.5f * (bf2f(vb.x) - bf2f(va.x)), 0.5f * (bf2f(vb.x >> 16) - bf2f(va.x >> 16)));
          o.y = pack2(0.5f * (bf2f(vb.y) - bf2f(va.y)), 0.5f * (bf2f(vb.y >> 16) - bf2f(va.y >> 16)));
          o.z = pack2(0.5f * (bf2f(vb.z) - bf2f(va.z)), 0.5f * (bf2f(vb.z >> 16) - bf2f(va.z >> 16)));
          o.w = pack2(0.5f * (bf2f(vb.w) - bf2f(va.w)), 0.5f * (bf2f(vb.w >> 16) - bf2f(va.w >> 16)));
        }
        *(uint4*)(sA + r * 256 + ((c * 16) ^ ((r & 7) << 4))) = o;
      }
    } else {
      const u16* asrc = (const u16*)(p ? Ap2 : Ap) + (size_t)g * NN * NFEAT;
      const uint4* a4 = (const uint4*)asrc;
      for (int i = tid; i < 2048; i += 256){
        int r = i >> 4, c = i & 15; int node = nb + r;
        uint4 v = {0, 0, 0, 0};
        if (node < NN) v = a4[(size_t)node * 16 + c];
        *(uint4*)(sA + r * 256 + ((c * 16) ^ ((r & 7) << 4))) = v;
      }
    }
    __syncthreads();
    #pragma unroll
    for (int k0 = 0; k0 < 128; k0 += 32){
      const int kb = 2 * (k0 + lh * 8);
      bf16x8 af[4], bfr[4];
      #pragma unroll
      for (int t = 0; t < 4; t++){
        int rm = wm + t * 16 + l15;
        af[t] = *reinterpret_cast<const bf16x8*>(sW + rm * 256 + (kb ^ ((rm & 7) << 4)));
        int rn = wn + t * 16 + l15;
        bfr[t] = *reinterpret_cast<const bf16x8*>(sA + rn * 256 + (kb ^ ((rn & 7) << 4)));
      }
      #pragma unroll
      for (int mi = 0; mi < 4; mi++)
        #pragma unroll
        for (int ni = 0; ni < 4; ni++)
          acc[mi][ni] = __builtin_amdgcn_mfma_f32_16x16x32_bf16(af[mi], bfr[ni], acc[mi][ni], 0, 0, 0);
    }
  }
  // per-ni node scale (dinv) loads — coalesced across l15
  float scn[4] = {1.f, 1.f, 1.f, 1.f};
  if (scale){
    const float* sg = scale + (size_t)g * NN;
    #pragma unroll
    for (int ni = 0; ni < 4; ni++){
      int node = nb + wn + ni * 16 + l15;
      scn[ni] = (node < NN) ? sg[node] : 0.f;
    }
  }
  u16* outg = Out + (size_t)g * NN * NFEAT;
  #pragma unroll
  for (int mi = 0; mi < 4; mi++){
    int mbase = wm + mi * 16 + lh * 4;
    f32x4 bv = {};
    if (hasBias) bv = *reinterpret_cast<const f32x4*>(bias + (biasPerG ? g * NFEAT : 0) + mbase);
    #pragma unroll
    for (int ni = 0; ni < 4; ni++){
      int node = nb + wn + ni * 16 + l15;
      if (node < NN){
        f32x4 v = acc[mi][ni];
        float s = scn[ni];
        ushort4 o;
        o.x = f2bf((v.x + bv.x) * s); o.y = f2bf((v.y + bv.y) * s);
        o.z = f2bf((v.z + bv.z) * s); o.w = f2bf((v.w + bv.w) * s);
        *reinterpret_cast<ushort4*>(outg + (size_t)node * NFEAT + mbase) = o;
      }
    }
  }
}

// ---------------------------------------------------------------------------
// GCN aggregation over PRE-SCALED h (hs = dinv*h):
//   out[v] = dinv[v] * (sum_{src in N(v)} hs[src] + hs[v]) + b
// Wave per node. 4 lane-groups x 16 lanes; each lane loads uint4 = 8 feats.
// One dwordx4 wave-load fetches 4 edge rows; 2 loads/iter => 8 edges in
// flight (2KB/wave). Butterfly shfl_xor(16,32) combines groups.
// Optional fused sum((Ref-out)^2) per graph.
// ---------------------------------------------------------------------------
template<bool SQ>
__global__ __launch_bounds__(256) void agg_kernel(
    const u16* H, u16* Outp, const float* bias, const float* dinv,
    const int* rowptr, const int* colidx, const u16* Ref, float* sqslot)
{
  const int g = blockIdx.y;
  const int v = blockIdx.x * 4 + (threadIdx.x >> 6);
  const int l = threadIdx.x & 63;
  const int q = l >> 4, sub = l & 15;
  const uint4* h4 = (const uint4*)(H + (size_t)g * NN * NFEAT);   // 16 uint4/row
  const int* rp = rowptr + g * (NN + 1);
  const int* ci = colidx + (size_t)g * NE;
  const int e0 = rp[v];
  const int nslot = rp[v + 1] - e0 + 1;   // slot 0 = self
  float a0=0,a1=0,a2=0,a3=0,a4=0,a5=0,a6=0,a7=0;
  const int nIter = (nslot + 7) >> 3;
  for (int it = 0; it < nIter; ++it){
    int sA = it * 8 + q;
    int sB = sA + 4;
    int srcA = (sA == 0) ? v : ((sA < nslot) ? ci[e0 + sA - 1] : v);
    int srcB = (sB < nslot) ? ci[e0 + sB - 1] : v;      // sB >= 4, never self-slot
    uint4 hA = h4[(size_t)srcA * 16 + sub];
    uint4 hB = h4[(size_t)srcB * 16 + sub];
    if (sA < nslot){
      a0 += bf2f(hA.x); a1 += bf2f(hA.x >> 16);
      a2 += bf2f(hA.y); a3 += bf2f(hA.y >> 16);
      a4 += bf2f(hA.z); a5 += bf2f(hA.z >> 16);
      a6 += bf2f(hA.w); a7 += bf2f(hA.w >> 16);
    }
    if (sB < nslot){
      a0 += bf2f(hB.x); a1 += bf2f(hB.x >> 16);
      a2 += bf2f(hB.y); a3 += bf2f(hB.y >> 16);
      a4 += bf2f(hB.z); a5 += bf2f(hB.z >> 16);
      a6 += bf2f(hB.w); a7 += bf2f(hB.w >> 16);
    }
  }
  // combine the 4 lane-groups
  a0 += __shfl_xor(a0, 16); a1 += __shfl_xor(a1, 16);
  a2 += __shfl_xor(a2, 16); a3 += __shfl_xor(a3, 16);
  a4 += __shfl_xor(a4, 16); a5 += __shfl_xor(a5, 16);
  a6 += __shfl_xor(a6, 16); a7 += __shfl_xor(a7, 16);
  a0 += __shfl_xor(a0, 32); a1 += __shfl_xor(a1, 32);
  a2 += __shfl_xor(a2, 32); a3 += __shfl_xor(a3, 32);
  a4 += __shfl_xor(a4, 32); a5 += __shfl_xor(a5, 32);
  a6 += __shfl_xor(a6, 32); a7 += __shfl_xor(a7, 32);
  const float dvv = dinv[(size_t)g * NN + v];
  const float4 b4a = *(const float4*)(bias + sub * 8);
  const float4 b4b = *(const float4*)(bias + sub * 8 + 4);
  a0 = a0 * dvv + b4a.x; a1 = a1 * dvv + b4a.y;
  a2 = a2 * dvv + b4a.z; a3 = a3 * dvv + b4a.w;
  a4 = a4 * dvv + b4b.x; a5 = a5 * dvv + b4b.y;
  a6 = a6 * dvv + b4b.z; a7 = a7 * dvv + b4b.w;
  float sq = 0.f;
  if (q == 0){
    uint4 o;
    o.x = pack2(a0, a1); o.y = pack2(a2, a3);
    o.z = pack2(a4, a5); o.w = pack2(a6, a7);
    ((uint4*)(Outp + (size_t)g * NN * NFEAT))[(size_t)v * 16 + sub] = o;
    if (SQ){
      uint4 rv = ((const uint4*)(Ref + (size_t)g * NN * NFEAT))[(size_t)v * 16 + sub];
      float d;
      d = bf2f(rv.x) - a0; sq += d * d; d = bf2f(rv.x >> 16) - a1; sq += d * d;
      d = bf2f(rv.y) - a2; sq += d * d; d = bf2f(rv.y >> 16) - a3; sq += d * d;
      d = bf2f(rv.z) - a4; sq += d * d; d = bf2f(rv.z >> 16) - a5; sq += d * d;
      d = bf2f(rv.w) - a6; sq += d * d; d = bf2f(rv.w >> 16) - a7; sq += d * d;
    }
  }
  if (SQ){
    __shared__ float red[4];
    sq += __shfl_xor(sq, 1); sq += __shfl_xor(sq, 2);
    sq += __shfl_xor(sq, 4); sq += __shfl_xor(sq, 8);
    if (l == 0) red[threadIdx.x >> 6] = sq;
    __syncthreads();
    if (threadIdx.x == 0)
      atomicAdd(sqslot + g, red[0] + red[1] + red[2] + red[3]);
  }
}

// ---------------------------------------------------------------------------
// enc_sum (bf16), used_feat = elu(enc_sum/3) -> d_out, colsum partials
// ---------------------------------------------------------------------------
__global__ __launch_bounds__(256) void encsum_kernel(
    const u16* Enc, u16* EncSum, float* outUsed, float* colsum)
{
  const int fp = threadIdx.x & 63, sub = threadIdx.x >> 6;
  const u32* e0 = (const u32*)Enc;
  const u32* e1 = e0 + (size_t)NN * 64;
  const u32* e2 = e1 + (size_t)NN * 64;
  u32* es = (u32*)EncSum;
  float cs[6] = {0, 0, 0, 0, 0, 0};
  for (int v = blockIdx.x * 4 + sub; v < NN; v += gridDim.x * 4){
    size_t idx = (size_t)v * 64 + fp;
    u32 a = e0[idx], b = e1[idx], c = e2[idx];
    float axv = bf2f(a), ayv = bf2f(a >> 16);
    float bxv = bf2f(b), byv = bf2f(b >> 16);
    float cxv = bf2f(c), cyv = bf2f(c >> 16);
    cs[0] += axv; cs[1] += ayv; cs[2] += bxv; cs[3] += byv; cs[4] += cxv; cs[5] += cyv;
    float sx = axv + bxv + cxv, sy = ayv + byv + cyv;
    es[idx] = pack2(sx, sy);
    float ux = sx * (1.f / 3.f), uy = sy * (1.f / 3.f);
    float2 o;
    o.x = ux > 0.f ? ux : expm1f(ux);
    o.y = uy > 0.f ? uy : expm1f(uy);
    *(float2*)(outUsed + (size_t)v * NFEAT + 2 * fp) = o;
  }
  __shared__ float red[256];
  #pragma unroll
  for (int q = 0; q < 6; q++){
    red[threadIdx.x] = cs[q];
    __syncthreads();
    if (sub == 0){
      float s = red[fp] + red[64 + fp] + red[128 + fp] + red[192 + fp];
      atomicAdd(&colsum[(q >> 1) * NFEAT + 2 * fp + (q & 1)], s);
    }
    __syncthreads();
  }
}

// global_vec = sigmoid(colsum/N); u[i] = att_w[i] @ global_vec[i]
__global__ void gvecu_kernel(const float* colsum, const float* att, float* u){
  __shared__ float gv[3 * 128];
  const int t = threadIdx.x;   // 128 threads
  for (int g = 0; g < 3; g++) gv[g * 128 + t] = sigm(colsum[g * 128 + t] * (1.f / 50000.f));
  __syncthreads();
  for (int i = 0; i < 3; i++){
    float s = 0.f;
    for (int e = 0; e < 128; e++)
      s += att[(size_t)i * 16384 + (size_t)t * 128 + e] * gv[i * 128 + e];
    u[i * 128 + t] = s;
  }
}

// fuse_feat = sigmoid(mean_g each_fin) -> d_out; pairwise sqdiffs -> slots[6..8]
__global__ __launch_bounds__(256) void fuse_kernel(const u16* EF, float* outFuse, float* slots){
  const int fp = threadIdx.x & 63, sub = threadIdx.x >> 6;
  const u32* e0 = (const u32*)EF;
  const u32* e1 = e0 + (size_t)NN * 64;
  const u32* e2 = e1 + (size_t)NN * 64;
  float s01 = 0, s02 = 0, s12 = 0;
  for (int v = blockIdx.x * 4 + sub; v < NN; v += gridDim.x * 4){
    size_t idx = (size_t)v * 64 + fp;
    u32 a = e0[idx], b = e1[idx], c = e2[idx];
    float axv = bf2f(a), ayv = bf2f(a >> 16), bxv = bf2f(b), byv = bf2f(b >> 16);
    float cxv = bf2f(c), cyv = bf2f(c >> 16);
    float2 o;
    o.x = sigm((axv + bxv + cxv) * (1.f / 3.f));
    o.y = sigm((ayv + byv + cyv) * (1.f / 3.f));
    *(float2*)(outFuse + (size_t)v * NFEAT + 2 * fp) = o;
    float dx, dy;
    dx = axv - bxv; dy = ayv - byv; s01 += dx * dx + dy * dy;
    dx = axv - cxv; dy = ayv - cyv; s02 += dx * dx + dy * dy;
    dx = bxv - cxv; dy = byv - cyv; s12 += dx * dx + dy * dy;
  }
  __shared__ float red[256];
  float vals[3] = {s01, s02, s12};
  #pragma unroll
  for (int q = 0; q < 3; q++){
    red[threadIdx.x] = vals[q];
    __syncthreads();
    for (int s2 = 128; s2 > 0; s2 >>= 1){
      if (threadIdx.x < s2) red[threadIdx.x] += red[threadIdx.x + s2];
      __syncthreads();
    }
    if (threadIdx.x == 0) atomicAdd(slots + 6 + q, red[0]);
    __syncthreads();
  }
}

// comp_re[n][i*3+j] = S[i,j,n] / sum_j S[i,j,n],  S = sigmoid(enc[j,n].u[i])
__global__ __launch_bounds__(256) void comp_kernel(const u16* Enc, const float* u, float* outC){
  __shared__ float su[384];
  for (int i = threadIdx.x; i < 384; i += 256) su[i] = u[i];
  __syncthreads();
  const int v = blockIdx.x * 4 + (threadIdx.x >> 6);
  const int l = threadIdx.x & 63;
  const u32* e = (const u32*)Enc;
  float ex[3], ey[3];
  #pragma unroll
  for (int j = 0; j < 3; j++){
    u32 t = e[((size_t)j * NN + v) * 64 + l];
    ex[j] = bf2f(t); ey[j] = bf2f(t >> 16);
  }
  float p[9];
  #pragma unroll
  for (int i = 0; i < 3; i++){
    float uxi = su[i * 128 + 2 * l], uyi = su[i * 128 + 2 * l + 1];
    #pragma unroll
    for (int j = 0; j < 3; j++)
      p[i * 3 + j] = ex[j] * uxi + ey[j] * uyi;
  }
  #pragma unroll
  for (int q = 0; q < 9; q++){
    float s = p[q];
    #pragma unroll
    for (int off = 1; off < 64; off <<= 1) s += __shfl_xor(s, off, 64);
    p[q] = s;
  }
  if (l < 9){
    float sg[9];
    #pragma unroll
    for (int q = 0; q < 9; q++) sg[q] = sigm(p[q]);
    float d0 = sg[0] + sg[1] + sg[2], d1 = sg[3] + sg[4] + sg[5], d2 = sg[6] + sg[7] + sg[8];
    float num = sg[0];
    if (l == 1) num = sg[1]; if (l == 2) num = sg[2]; if (l == 3) num = sg[3];
    if (l == 4) num = sg[4]; if (l == 5) num = sg[5]; if (l == 6) num = sg[6];
    if (l == 7) num = sg[7]; if (l == 8) num = sg[8];
    float den = (l < 3) ? d0 : (l < 6) ? d1 : d2;
    outC[(size_t)v * 9 + l] = num / den;
  }
}

// obf1/obf0 final assembly
__global__ void final_kernel(const float* slots, float* out){
  if (threadIdx.x == 0){
    float obf1 = 0.f;
    for (int g = 0; g < 3; g++)
      obf1 += 0.5f * (sqrtf(slots[3 + g]) + sqrtf(slots[g]));
    float obf0 = 2.f * (sqrtf(slots[6]) + sqrtf(slots[7]) + sqrtf(slots[8]));
    out[13250000] = obf1;
    out[13250001] = obf0;
  }
}

// ---------------------------------------------------------------------------
extern "C" void kernel_launch(void* const* d_in, const int* in_sizes, int n_in,
                              void* d_out, int out_size, void* d_ws, size_t ws_size,
                              hipStream_t stream)
{
  (void)in_sizes; (void)n_in; (void)out_size;
  const float* x    = (const float*)d_in[0];
  const float* fc1w = (const float*)d_in[1];
  const float* fc1b = (const float*)d_in[2];
  const float* wc1  = (const float*)d_in[3];
  const float* bc1  = (const float*)d_in[4];
  const float* wc2  = (const float*)d_in[5];
  const float* bc2  = (const float*)d_in[6];
  const float* wd1  = (const float*)d_in[7];
  const float* bd1  = (const float*)d_in[8];
  const float* wd2  = (const float*)d_in[9];
  const float* bd2  = (const float*)d_in[10];
  const float* fc2w = (const float*)d_in[11];
  const float* fc2b = (const float*)d_in[12];
  const float* attw = (const float*)d_in[13];
  const int*   ei   = (const int*)d_in[14];
  float* out = (float*)d_out;
  char* ws = (char*)d_ws;

  constexpr size_t BUFB = (size_t)NG * NN * NFEAT * 2;   // 38,400,000 B per act buffer
  u16* WT   = (u16*)(ws + 0);
  u16* buf0 = (u16*)(ws + 327680);
  u16* buf1 = (u16*)(ws + 327680 + 1 * BUFB);
  u16* buf2 = (u16*)(ws + 327680 + 2 * BUFB);
  u16* buf3 = (u16*)(ws + 327680 + 3 * BUFB);
  u16* buf4 = (u16*)(ws + 327680 + 4 * BUFB);
  u16* buf5 = (u16*)(ws + 327680 + 5 * BUFB);
  size_t off = 327680 + 6 * BUFB;
  u16* encsum = (u16*)(ws + off); off += (size_t)NN * NFEAT * 2;
  float* dinv = (float*)(ws + off); off += (size_t)NG * NN * 4;
  int* rowptr = (int*)(ws + off); off += 600064;
  int* colbuf = (int*)(ws + off); off += (size_t)NG * NE * 4;
  size_t zero_off = off;
  int* deg     = (int*)(ws + off); off += (size_t)NG * NN * 4;
  int* cursor  = (int*)(ws + off); off += (size_t)NG * NN * 4;
  float* colsum = (float*)(ws + off); off += 1536;
  float* slots  = (float*)(ws + off); off += 64;
  size_t zero_bytes = off - zero_off;
  float* uvec = (float*)(ws + off); off += 1536;
  if (ws_size < off) return;   // workspace too small: fail loudly without OOB writes

  hipMemsetAsync(ws + zero_off, 0, zero_bytes, stream);

  wprep_kernel<<<576, 256, 0, stream>>>(fc1w, wc1, wc2, wd1, wd2, fc2w, WT);
  deg_kernel<<<7032, 256, 0, stream>>>(ei, deg);
  scan_kernel<<<NG, 1024, 0, stream>>>(deg, rowptr, dinv);
  fill_kernel<<<7032, 256, 0, stream>>>(ei, rowptr, cursor, colbuf);

  const u16* WT_fc1 = WT;
  const u16* WT_c1  = WT + 49152;
  const u16* WT_c2  = WT + 65536;
  const u16* WT_d1  = WT + 81920;
  const u16* WT_d2  = WT + 98304;
  const u16* WT_f2a = WT + 114688;
  const u16* WT_f2b = WT + 131072;
  dim3 gg(391, NG), ag(12500, NG);

  // pre_feat = x @ fc1_w + fc1_b                      -> buf0 (unscaled)
  gemm_kernel<1><<<gg, 256, 0, stream>>>(x, nullptr, WT_fc1, nullptr, fc1b, buf0, nullptr, 1, 1, 1);
  // conv1_f = GCN(pre_feat, wc1, bc1)                 -> buf1
  gemm_kernel<0><<<gg, 256, 0, stream>>>(buf0, nullptr, WT_c1, nullptr, nullptr, buf3, dinv, 0, 0, 0);
  agg_kernel<false><<<ag, 256, 0, stream>>>(buf3, buf1, bc1, dinv, rowptr, colbuf, nullptr, nullptr);
  // enc = GCN(conv1_f, wc2, bc2)                      -> buf2
  gemm_kernel<0><<<gg, 256, 0, stream>>>(buf1, nullptr, WT_c2, nullptr, nullptr, buf3, dinv, 0, 0, 0);
  agg_kernel<false><<<ag, 256, 0, stream>>>(buf3, buf2, bc2, dinv, rowptr, colbuf, nullptr, nullptr);
  // enc_sum / used_feat / colsum ; global_vec -> u
  encsum_kernel<<<256, 256, 0, stream>>>(buf2, encsum, out + 6400000, colsum);
  gvecu_kernel<<<1, 128, 0, stream>>>(colsum, attw, uvec);
  // own1 = GCN(enc, wd1, bd1)  + sq(conv1_f-own1)     -> buf4, slots[0..2]
  gemm_kernel<0><<<gg, 256, 0, stream>>>(buf2, nullptr, WT_d1, nullptr, nullptr, buf3, dinv, 0, 0, 0);
  agg_kernel<true><<<ag, 256, 0, stream>>>(buf3, buf4, bd1, dinv, rowptr, colbuf, buf1, slots + 0);
  // own2 = GCN(own1, wd2, bd2) + sq(pre_feat-own2)    -> buf5, slots[3..5]
  gemm_kernel<0><<<gg, 256, 0, stream>>>(buf4, nullptr, WT_d2, nullptr, nullptr, buf3, dinv, 0, 0, 0);
  agg_kernel<true><<<ag, 256, 0, stream>>>(buf3, buf5, bd2, dinv, rowptr, colbuf, buf0, slots + 3);
  // oth1 = GCN((enc_sum-enc)/2, wd1, bd1)             -> buf1 (conv1_f dead)
  gemm_kernel<2><<<gg, 256, 0, stream>>>(buf2, encsum, WT_d1, nullptr, nullptr, buf3, dinv, 0, 0, 0);
  agg_kernel<false><<<ag, 256, 0, stream>>>(buf3, buf1, bd1, dinv, rowptr, colbuf, nullptr, nullptr);
  // oth2 = GCN(oth1, wd2, bd2)                        -> buf4 (own1 dead)
  gemm_kernel<0><<<gg, 256, 0, stream>>>(buf1, nullptr, WT_d2, nullptr, nullptr, buf3, dinv, 0, 0, 0);
  agg_kernel<false><<<ag, 256, 0, stream>>>(buf3, buf4, bd2, dinv, rowptr, colbuf, nullptr, nullptr);
  // each_fin = [own2|oth2] @ fc2_w + fc2_b            -> buf0 (pre_feat dead)
  gemm_kernel<3><<<gg, 256, 0, stream>>>(buf5, buf4, WT_f2a, WT_f2b, fc2b, buf0, nullptr, 0, 0, 1);
  // fuse_feat + obf0 pair sums
  fuse_kernel<<<256, 256, 0, stream>>>(buf0, out, slots);
  // comp_re
  comp_kernel<<<12500, 256, 0, stream>>>(buf2, uvec, out + 12800000);
  final_kernel<<<1, 64, 0, stream>>>(slots, out);
}

// Round 6
// 1946.005 us; speedup vs baseline: 1.1485x; 1.0680x over previous
//
#include <hip/hip_runtime.h>

#define NN 50000
#define NFEAT 128
#define NG 3
#define NE 600000

typedef unsigned int u32;
typedef unsigned short u16;
typedef __bf16 bf16x8 __attribute__((ext_vector_type(8)));
typedef float f32x4 __attribute__((ext_vector_type(4)));

__device__ __forceinline__ u16 f2bf(float f){
  u32 u = __float_as_uint(f);
  return (u16)((u + 0x7fffu + ((u >> 16) & 1u)) >> 16);   // RNE f32->bf16
}
__device__ __forceinline__ float bf2f(u32 s){
  return __uint_as_float((s & 0xffffu) << 16);
}
__device__ __forceinline__ u32 pack2(float a, float b){
  return (u32)f2bf(a) | ((u32)f2bf(b) << 16);
}
__device__ __forceinline__ float sigm(float x){ return 1.f / (1.f + __expf(-x)); }

// ---------------------------------------------------------------------------
// Weight prep: transpose+convert all weight matrices to bf16 Wt[c][k]
// ---------------------------------------------------------------------------
__global__ void wprep_kernel(const float* fc1w, const float* wc1, const float* wc2,
                             const float* wd1, const float* wd2, const float* fc2w,
                             u16* WT){
  int idx = blockIdx.x * 256 + threadIdx.x;
  if (idx >= 147456) return;
  float v;
  if (idx < 49152){
    int g = idx / 16384, r = idx % 16384; int o = r / 128, f = r % 128;
    v = fc1w[g * 16384 + f * 128 + o];
  } else if (idx < 114688){
    int m = (idx - 49152) / 16384, r = (idx - 49152) % 16384;
    int o = r / 128, f = r % 128;
    const float* w = (m == 0) ? wc1 : (m == 1) ? wc2 : (m == 2) ? wd1 : wd2;
    v = w[f * 128 + o];
  } else {
    int r = idx - 114688; int half = r / 16384; r %= 16384;
    int o = r / 128, f = r % 128;
    v = fc2w[(half * 128 + f) * 128 + o];
  }
  WT[idx] = f2bf(v);
}

// ---------------------------------------------------------------------------
// CSR build
// ---------------------------------------------------------------------------
__global__ void deg_kernel(const int* ei, int* deg){
  int t = blockIdx.x * 256 + threadIdx.x;
  if (t >= NG * NE) return;
  int g = t / NE, e = t - g * NE;
  int dst = ei[(size_t)g * 2 * NE + NE + e];
  atomicAdd(deg + (size_t)g * NN + dst, 1);
}

__global__ __launch_bounds__(1024) void scan_kernel(const int* deg, int* rowptr, float* dinv){
  const int g = blockIdx.x;
  const int* d = deg + (size_t)g * NN;
  int* rp = rowptr + g * (NN + 1);
  float* di = dinv + (size_t)g * NN;
  __shared__ int s[1024];
  __shared__ int carry;
  if (threadIdx.x == 0) carry = 0;
  __syncthreads();
  for (int base = 0; base <= NN; base += 1024){
    int idx = base + threadIdx.x;
    int v = (idx < NN) ? d[idx] : 0;
    if (idx < NN) di[idx] = rsqrtf((float)(v + 1));   // deg includes self-loop
    s[threadIdx.x] = v;
    __syncthreads();
    for (int off = 1; off < 1024; off <<= 1){
      int x = (threadIdx.x >= off) ? s[threadIdx.x - off] : 0;
      __syncthreads();
      s[threadIdx.x] += x;
      __syncthreads();
    }
    int incl = s[threadIdx.x];
    int run = carry;
    if (idx <= NN) rp[idx] = run + incl - v;   // exclusive
    __syncthreads();
    if (threadIdx.x == 1023) carry = run + s[1023];
    __syncthreads();
  }
}

__global__ void fill_kernel(const int* ei, const int* rowptr, int* cursor, int* colbuf){
  int t = blockIdx.x * 256 + threadIdx.x;
  if (t >= NG * NE) return;
  int g = t / NE, e = t - g * NE;
  int src = ei[(size_t)g * 2 * NE + e];
  int dst = ei[(size_t)g * 2 * NE + NE + e];
  int pos = atomicAdd(cursor + (size_t)g * NN + dst, 1);
  colbuf[(size_t)g * NE + rowptr[g * (NN + 1) + dst] + pos] = src;
}

// ---------------------------------------------------------------------------
// GEMM: Out[g][n][c] = (sum_k A[g][n][k] * W[k][c] (+bias)) * (scale?dinv[n]:1)
// MFMA-A = Wt (m=feature), MFMA-B = activations (n=node).
// outStride16/outOff16 (u16 units) let two passes write [own|oth] fused rows.
// aPerG=0 => A is a single shared NN x 128 buffer (e.g. enc_sum).
// MODE 0: A bf16. MODE 1: A f32 (x). MODE 3: two passes K=256 (each_fin).
// ---------------------------------------------------------------------------
template<int MODE>
__global__ __launch_bounds__(256, 2) void gemm_kernel(
    const void* Ap, const void* Ap2, const u16* W, const u16* W2,
    const float* bias, u16* Out, const float* scale,
    int wPerG, int biasPerG, int hasBias, int outStride16, int outOff16, int aPerG)
{
  __shared__ __align__(16) unsigned char sA[128 * 256];
  __shared__ __align__(16) unsigned char sW[128 * 256];
  const int tid = threadIdx.x;
  const int g = blockIdx.y;
  const int nb = blockIdx.x * 128;
  const int lane = tid & 63, wv = tid >> 6;
  const int wm = (wv & 1) * 64, wn = (wv >> 1) * 64;
  const int l15 = lane & 15, lh = lane >> 4;
  f32x4 acc[4][4] = {};
  constexpr int passes = (MODE == 3) ? 2 : 1;
  for (int p = 0; p < passes; p++){
    if (p) __syncthreads();
    { // stage W tile [feat][128] bf16 (pre-transposed), swizzled
      const u16* wsrc = (p ? W2 : W) + (wPerG ? g * 16384 : 0);
      const uint4* w4 = (const uint4*)wsrc;
      for (int i = tid; i < 2048; i += 256){
        int r = i >> 4, c = i & 15;
        uint4 v = w4[i];
        *(uint4*)(sW + r * 256 + ((c * 16) ^ ((r & 7) << 4))) = v;
      }
    }
    if (MODE == 1){
      const float* xp = (const float*)Ap + (size_t)g * NN * NFEAT;
      for (int i = tid; i < 2048; i += 256){
        int r = i >> 4, c = i & 15; int node = nb + r;
        uint4 o = {0, 0, 0, 0};
        if (node < NN){
          const float* row = xp + (size_t)node * NFEAT + c * 8;
          float4 a4 = *(const float4*)row;
          float4 b4 = *(const float4*)(row + 4);
          o.x = pack2(a4.x, a4.y); o.y = pack2(a4.z, a4.w);
          o.z = pack2(b4.x, b4.y); o.w = pack2(b4.z, b4.w);
        }
        *(uint4*)(sA + r * 256 + ((c * 16) ^ ((r & 7) << 4))) = o;
      }
    } else {
      const u16* asrc = (const u16*)(p ? Ap2 : Ap) + (aPerG ? (size_t)g * NN * NFEAT : 0);
      const uint4* a4 = (const uint4*)asrc;
      for (int i = tid; i < 2048; i += 256){
        int r = i >> 4, c = i & 15; int node = nb + r;
        uint4 v = {0, 0, 0, 0};
        if (node < NN) v = a4[(size_t)node * 16 + c];
        *(uint4*)(sA + r * 256 + ((c * 16) ^ ((r & 7) << 4))) = v;
      }
    }
    __syncthreads();
    #pragma unroll
    for (int k0 = 0; k0 < 128; k0 += 32){
      const int kb = 2 * (k0 + lh * 8);
      bf16x8 af[4], bfr[4];
      #pragma unroll
      for (int t = 0; t < 4; t++){
        int rm = wm + t * 16 + l15;
        af[t] = *reinterpret_cast<const bf16x8*>(sW + rm * 256 + (kb ^ ((rm & 7) << 4)));
        int rn = wn + t * 16 + l15;
        bfr[t] = *reinterpret_cast<const bf16x8*>(sA + rn * 256 + (kb ^ ((rn & 7) << 4)));
      }
      #pragma unroll
      for (int mi = 0; mi < 4; mi++)
        #pragma unroll
        for (int ni = 0; ni < 4; ni++)
          acc[mi][ni] = __builtin_amdgcn_mfma_f32_16x16x32_bf16(af[mi], bfr[ni], acc[mi][ni], 0, 0, 0);
    }
  }
  // per-ni node scale (dinv) loads — coalesced across l15
  float scn[4] = {1.f, 1.f, 1.f, 1.f};
  if (scale){
    const float* sg = scale + (size_t)g * NN;
    #pragma unroll
    for (int ni = 0; ni < 4; ni++){
      int node = nb + wn + ni * 16 + l15;
      scn[ni] = (node < NN) ? sg[node] : 0.f;
    }
  }
  u16* outg = Out + (size_t)g * NN * outStride16;
  #pragma unroll
  for (int mi = 0; mi < 4; mi++){
    int mbase = wm + mi * 16 + lh * 4;
    f32x4 bv = {};
    if (hasBias) bv = *reinterpret_cast<const f32x4*>(bias + (biasPerG ? g * NFEAT : 0) + mbase);
    #pragma unroll
    for (int ni = 0; ni < 4; ni++){
      int node = nb + wn + ni * 16 + l15;
      if (node < NN){
        f32x4 v = acc[mi][ni];
        float s = scn[ni];
        ushort4 o;
        o.x = f2bf((v.x + bv.x) * s); o.y = f2bf((v.y + bv.y) * s);
        o.z = f2bf((v.z + bv.z) * s); o.w = f2bf((v.w + bv.w) * s);
        *reinterpret_cast<ushort4*>(outg + (size_t)node * outStride16 + outOff16 + mbase) = o;
      }
    }
  }
}

// ---------------------------------------------------------------------------
// GCN aggregation over PRE-SCALED h (hs = dinv*h), 256B rows (encoder):
//   out[v] = dinv[v] * (sum_nbr hs[src] + hs[v]) + b
// Wave per node; 4 groups x 16 lanes; lane = uint4 (8 feats).
// ---------------------------------------------------------------------------
__global__ __launch_bounds__(256) void agg_kernel(
    const u16* H, u16* Outp, const float* bias, const float* dinv,
    const int* rowptr, const int* colidx)
{
  const int g = blockIdx.y;
  const int v = blockIdx.x * 4 + (threadIdx.x >> 6);
  const int l = threadIdx.x & 63;
  const int q = l >> 4, sub = l & 15;
  const uint4* h4 = (const uint4*)(H + (size_t)g * NN * NFEAT);   // 16 uint4/row
  const int* rp = rowptr + g * (NN + 1);
  const int* ci = colidx + (size_t)g * NE;
  const int e0 = rp[v];
  const int nslot = rp[v + 1] - e0 + 1;   // slot 0 = self
  float aa[8] = {0,0,0,0,0,0,0,0};
  const int nIter = (nslot + 7) >> 3;
  for (int it = 0; it < nIter; ++it){
    int sA = it * 8 + q;
    int sB = sA + 4;
    int srcA = (sA == 0) ? v : ((sA < nslot) ? ci[e0 + sA - 1] : v);
    int srcB = (sB < nslot) ? ci[e0 + sB - 1] : v;
    uint4 hA = h4[(size_t)srcA * 16 + sub];
    uint4 hB = h4[(size_t)srcB * 16 + sub];
    if (sA < nslot){
      aa[0] += bf2f(hA.x); aa[1] += bf2f(hA.x >> 16);
      aa[2] += bf2f(hA.y); aa[3] += bf2f(hA.y >> 16);
      aa[4] += bf2f(hA.z); aa[5] += bf2f(hA.z >> 16);
      aa[6] += bf2f(hA.w); aa[7] += bf2f(hA.w >> 16);
    }
    if (sB < nslot){
      aa[0] += bf2f(hB.x); aa[1] += bf2f(hB.x >> 16);
      aa[2] += bf2f(hB.y); aa[3] += bf2f(hB.y >> 16);
      aa[4] += bf2f(hB.z); aa[5] += bf2f(hB.z >> 16);
      aa[6] += bf2f(hB.w); aa[7] += bf2f(hB.w >> 16);
    }
  }
  #pragma unroll
  for (int i = 0; i < 8; i++){
    aa[i] += __shfl_xor(aa[i], 16);
    aa[i] += __shfl_xor(aa[i], 32);
  }
  if (q == 0){
    const float dvv = dinv[(size_t)g * NN + v];
    const float4 b4a = *(const float4*)(bias + sub * 8);
    const float4 b4b = *(const float4*)(bias + sub * 8 + 4);
    uint4 o;
    o.x = pack2(aa[0] * dvv + b4a.x, aa[1] * dvv + b4a.y);
    o.y = pack2(aa[2] * dvv + b4a.z, aa[3] * dvv + b4a.w);
    o.z = pack2(aa[4] * dvv + b4b.x, aa[5] * dvv + b4b.y);
    o.w = pack2(aa[6] * dvv + b4b.z, aa[7] * dvv + b4b.w);
    ((uint4*)(Outp + (size_t)g * NN * NFEAT))[(size_t)v * 16 + sub] = o;
  }
}

// ---------------------------------------------------------------------------
// FUSED dual aggregation over 512B rows F[node] = [ownHalf(128) | othHalf(128)]:
//   U = sum_slots ownHalf, T = sum_slots othHalf  (slot 0 = self)
//   own[v] = dvv*U + b
//   oth[v] = COMB ? 0.5*dvv*(T-U) + b : dvv*T + b
// SQ: sum((Ref - own)^2) -> atomicAdd(sqslot[g]). Ref may alias OutOwn/OutOth
// (same-row read-before-write within the owning thread only).
// ---------------------------------------------------------------------------
template<int COMB, bool SQ>
__global__ __launch_bounds__(256) void agg2_kernel(
    const u16* F, u16* OutOwn, u16* OutOth, const float* bias, const float* dinv,
    const int* rowptr, const int* colidx, const u16* Ref, float* sqslot)
{
  const int g = blockIdx.y;
  const int v = blockIdx.x * 4 + (threadIdx.x >> 6);
  const int l = threadIdx.x & 63;
  const int q = l >> 4, sub = l & 15;
  const uint4* h4 = (const uint4*)(F + (size_t)g * NN * 256);   // 32 uint4/row
  const int* rp = rowptr + g * (NN + 1);
  const int* ci = colidx + (size_t)g * NE;
  const int e0 = rp[v];
  const int nslot = rp[v + 1] - e0 + 1;   // slot 0 = self
  float uu[8] = {0,0,0,0,0,0,0,0};
  float tt[8] = {0,0,0,0,0,0,0,0};
  const int nIter = (nslot + 7) >> 3;
  for (int it = 0; it < nIter; ++it){
    int sA = it * 8 + q;
    int sB = sA + 4;
    int srcA = (sA == 0) ? v : ((sA < nslot) ? ci[e0 + sA - 1] : v);
    int srcB = (sB < nslot) ? ci[e0 + sB - 1] : v;
    uint4 uA = h4[(size_t)srcA * 32 + sub];
    uint4 tA = h4[(size_t)srcA * 32 + 16 + sub];
    uint4 uB = h4[(size_t)srcB * 32 + sub];
    uint4 tB = h4[(size_t)srcB * 32 + 16 + sub];
    if (sA < nslot){
      uu[0] += bf2f(uA.x); uu[1] += bf2f(uA.x >> 16);
      uu[2] += bf2f(uA.y); uu[3] += bf2f(uA.y >> 16);
      uu[4] += bf2f(uA.z); uu[5] += bf2f(uA.z >> 16);
      uu[6] += bf2f(uA.w); uu[7] += bf2f(uA.w >> 16);
      tt[0] += bf2f(tA.x); tt[1] += bf2f(tA.x >> 16);
      tt[2] += bf2f(tA.y); tt[3] += bf2f(tA.y >> 16);
      tt[4] += bf2f(tA.z); tt[5] += bf2f(tA.z >> 16);
      tt[6] += bf2f(tA.w); tt[7] += bf2f(tA.w >> 16);
    }
    if (sB < nslot){
      uu[0] += bf2f(uB.x); uu[1] += bf2f(uB.x >> 16);
      uu[2] += bf2f(uB.y); uu[3] += bf2f(uB.y >> 16);
      uu[4] += bf2f(uB.z); uu[5] += bf2f(uB.z >> 16);
      uu[6] += bf2f(uB.w); uu[7] += bf2f(uB.w >> 16);
      tt[0] += bf2f(tB.x); tt[1] += bf2f(tB.x >> 16);
      tt[2] += bf2f(tB.y); tt[3] += bf2f(tB.y >> 16);
      tt[4] += bf2f(tB.z); tt[5] += bf2f(tB.z >> 16);
      tt[6] += bf2f(tB.w); tt[7] += bf2f(tB.w >> 16);
    }
  }
  #pragma unroll
  for (int i = 0; i < 8; i++){
    uu[i] += __shfl_xor(uu[i], 16); uu[i] += __shfl_xor(uu[i], 32);
    tt[i] += __shfl_xor(tt[i], 16); tt[i] += __shfl_xor(tt[i], 32);
  }
  const float dvv = dinv[(size_t)g * NN + v];
  const float4 b4a = *(const float4*)(bias + sub * 8);
  const float4 b4b = *(const float4*)(bias + sub * 8 + 4);
  float own[8], oth[8];
  const float bb[8] = {b4a.x, b4a.y, b4a.z, b4a.w, b4b.x, b4b.y, b4b.z, b4b.w};
  #pragma unroll
  for (int i = 0; i < 8; i++){
    own[i] = uu[i] * dvv + bb[i];
    if (COMB) oth[i] = (tt[i] - uu[i]) * dvv * 0.5f + bb[i];
    else      oth[i] = tt[i] * dvv + bb[i];
  }
  float sq = 0.f;
  if (q == 0){
    if (SQ){
      uint4 rv = ((const uint4*)(Ref + (size_t)g * NN * NFEAT))[(size_t)v * 16 + sub];
      float d;
      d = bf2f(rv.x) - own[0]; sq += d * d; d = bf2f(rv.x >> 16) - own[1]; sq += d * d;
      d = bf2f(rv.y) - own[2]; sq += d * d; d = bf2f(rv.y >> 16) - own[3]; sq += d * d;
      d = bf2f(rv.z) - own[4]; sq += d * d; d = bf2f(rv.z >> 16) - own[5]; sq += d * d;
      d = bf2f(rv.w) - own[6]; sq += d * d; d = bf2f(rv.w >> 16) - own[7]; sq += d * d;
    }
    uint4 o;
    o.x = pack2(own[0], own[1]); o.y = pack2(own[2], own[3]);
    o.z = pack2(own[4], own[5]); o.w = pack2(own[6], own[7]);
    ((uint4*)(OutOwn + (size_t)g * NN * NFEAT))[(size_t)v * 16 + sub] = o;
    uint4 o2;
    o2.x = pack2(oth[0], oth[1]); o2.y = pack2(oth[2], oth[3]);
    o2.z = pack2(oth[4], oth[5]); o2.w = pack2(oth[6], oth[7]);
    ((uint4*)(OutOth + (size_t)g * NN * NFEAT))[(size_t)v * 16 + sub] = o2;
  }
  if (SQ){
    __shared__ float red[4];
    sq += __shfl_xor(sq, 1); sq += __shfl_xor(sq, 2);
    sq += __shfl_xor(sq, 4); sq += __shfl_xor(sq, 8);
    if (l == 0) red[threadIdx.x >> 6] = sq;
    __syncthreads();
    if (threadIdx.x == 0)
      atomicAdd(sqslot + g, red[0] + red[1] + red[2] + red[3]);
  }
}

// ---------------------------------------------------------------------------
// enc_sum (bf16), used_feat = elu(enc_sum/3) -> d_out, colsum partials
// ---------------------------------------------------------------------------
__global__ __launch_bounds__(256) void encsum_kernel(
    const u16* Enc, u16* EncSum, float* outUsed, float* colsum)
{
  const int fp = threadIdx.x & 63, sub = threadIdx.x >> 6;
  const u32* e0 = (const u32*)Enc;
  const u32* e1 = e0 + (size_t)NN * 64;
  const u32* e2 = e1 + (size_t)NN * 64;
  u32* es = (u32*)EncSum;
  float cs[6] = {0, 0, 0, 0, 0, 0};
  for (int v = blockIdx.x * 4 + sub; v < NN; v += gridDim.x * 4){
    size_t idx = (size_t)v * 64 + fp;
    u32 a = e0[idx], b = e1[idx], c = e2[idx];
    float axv = bf2f(a), ayv = bf2f(a >> 16);
    float bxv = bf2f(b), byv = bf2f(b >> 16);
    float cxv = bf2f(c), cyv = bf2f(c >> 16);
    cs[0] += axv; cs[1] += ayv; cs[2] += bxv; cs[3] += byv; cs[4] += cxv; cs[5] += cyv;
    float sx = axv + bxv + cxv, sy = ayv + byv + cyv;
    es[idx] = pack2(sx, sy);
    float ux = sx * (1.f / 3.f), uy = sy * (1.f / 3.f);
    float2 o;
    o.x = ux > 0.f ? ux : expm1f(ux);
    o.y = uy > 0.f ? uy : expm1f(uy);
    *(float2*)(outUsed + (size_t)v * NFEAT + 2 * fp) = o;
  }
  __shared__ float red[256];
  #pragma unroll
  for (int q = 0; q < 6; q++){
    red[threadIdx.x] = cs[q];
    __syncthreads();
    if (sub == 0){
      float s = red[fp] + red[64 + fp] + red[128 + fp] + red[192 + fp];
      atomicAdd(&colsum[(q >> 1) * NFEAT + 2 * fp + (q & 1)], s);
    }
    __syncthreads();
  }
}

// global_vec = sigmoid(colsum/N); u[i] = att_w[i] @ global_vec[i]
__global__ void gvecu_kernel(const float* colsum, const float* att, float* u){
  __shared__ float gv[3 * 128];
  const int t = threadIdx.x;   // 128 threads
  for (int g = 0; g < 3; g++) gv[g * 128 + t] = sigm(colsum[g * 128 + t] * (1.f / 50000.f));
  __syncthreads();
  for (int i = 0; i < 3; i++){
    float s = 0.f;
    for (int e = 0; e < 128; e++)
      s += att[(size_t)i * 16384 + (size_t)t * 128 + e] * gv[i * 128 + e];
    u[i * 128 + t] = s;
  }
}

// fuse_feat = sigmoid(mean_g each_fin) -> d_out; pairwise sqdiffs -> slots[6..8]
__global__ __launch_bounds__(256) void fuse_kernel(const u16* EF, float* outFuse, float* slots){
  const int fp = threadIdx.x & 63, sub = threadIdx.x >> 6;
  const u32* e0 = (const u32*)EF;
  const u32* e1 = e0 + (size_t)NN * 64;
  const u32* e2 = e1 + (size_t)NN * 64;
  float s01 = 0, s02 = 0, s12 = 0;
  for (int v = blockIdx.x * 4 + sub; v < NN; v += gridDim.x * 4){
    size_t idx = (size_t)v * 64 + fp;
    u32 a = e0[idx], b = e1[idx], c = e2[idx];
    float axv = bf2f(a), ayv = bf2f(a >> 16), bxv = bf2f(b), byv = bf2f(b >> 16);
    float cxv = bf2f(c), cyv = bf2f(c >> 16);
    float2 o;
    o.x = sigm((axv + bxv + cxv) * (1.f / 3.f));
    o.y = sigm((ayv + byv + cyv) * (1.f / 3.f));
    *(float2*)(outFuse + (size_t)v * NFEAT + 2 * fp) = o;
    float dx, dy;
    dx = axv - bxv; dy = ayv - byv; s01 += dx * dx + dy * dy;
    dx = axv - cxv; dy = ayv - cyv; s02 += dx * dx + dy * dy;
    dx = bxv - cxv; dy = byv - cyv; s12 += dx * dx + dy * dy;
  }
  __shared__ float red[256];
  float vals[3] = {s01, s02, s12};
  #pragma unroll
  for (int q = 0; q < 3; q++){
    red[threadIdx.x] = vals[q];
    __syncthreads();
    for (int s2 = 128; s2 > 0; s2 >>= 1){
      if (threadIdx.x < s2) red[threadIdx.x] += red[threadIdx.x + s2];
      __syncthreads();
    }
    if (threadIdx.x == 0) atomicAdd(slots + 6 + q, red[0]);
    __syncthreads();
  }
}

// comp_re[n][i*3+j] = S[i,j,n] / sum_j S[i,j,n],  S = sigmoid(enc[j,n].u[i])
__global__ __launch_bounds__(256) void comp_kernel(const u16* Enc, const float* u, float* outC){
  __shared__ float su[384];
  for (int i = threadIdx.x; i < 384; i += 256) su[i] = u[i];
  __syncthreads();
  const int v = blockIdx.x * 4 + (threadIdx.x >> 6);
  const int l = threadIdx.x & 63;
  const u32* e = (const u32*)Enc;
  float ex[3], ey[3];
  #pragma unroll
  for (int j = 0; j < 3; j++){
    u32 t = e[((size_t)j * NN + v) * 64 + l];
    ex[j] = bf2f(t); ey[j] = bf2f(t >> 16);
  }
  float p[9];
  #pragma unroll
  for (int i = 0; i < 3; i++){
    float uxi = su[i * 128 + 2 * l], uyi = su[i * 128 + 2 * l + 1];
    #pragma unroll
    for (int j = 0; j < 3; j++)
      p[i * 3 + j] = ex[j] * uxi + ey[j] * uyi;
  }
  #pragma unroll
  for (int q = 0; q < 9; q++){
    float s = p[q];
    #pragma unroll
    for (int off = 1; off < 64; off <<= 1) s += __shfl_xor(s, off, 64);
    p[q] = s;
  }
  if (l < 9){
    float sg[9];
    #pragma unroll
    for (int q = 0; q < 9; q++) sg[q] = sigm(p[q]);
    float d0 = sg[0] + sg[1] + sg[2], d1 = sg[3] + sg[4] + sg[5], d2 = sg[6] + sg[7] + sg[8];
    float num = sg[0];
    if (l == 1) num = sg[1]; if (l == 2) num = sg[2]; if (l == 3) num = sg[3];
    if (l == 4) num = sg[4]; if (l == 5) num = sg[5]; if (l == 6) num = sg[6];
    if (l == 7) num = sg[7]; if (l == 8) num = sg[8];
    float den = (l < 3) ? d0 : (l < 6) ? d1 : d2;
    outC[(size_t)v * 9 + l] = num / den;
  }
}

// obf1/obf0 final assembly
__global__ void final_kernel(const float* slots, float* out){
  if (threadIdx.x == 0){
    float obf1 = 0.f;
    for (int g = 0; g < 3; g++)
      obf1 += 0.5f * (sqrtf(slots[3 + g]) + sqrtf(slots[g]));
    float obf0 = 2.f * (sqrtf(slots[6]) + sqrtf(slots[7]) + sqrtf(slots[8]));
    out[13250000] = obf1;
    out[13250001] = obf0;
  }
}

// ---------------------------------------------------------------------------
extern "C" void kernel_launch(void* const* d_in, const int* in_sizes, int n_in,
                              void* d_out, int out_size, void* d_ws, size_t ws_size,
                              hipStream_t stream)
{
  (void)in_sizes; (void)n_in; (void)out_size;
  const float* x    = (const float*)d_in[0];
  const float* fc1w = (const float*)d_in[1];
  const float* fc1b = (const float*)d_in[2];
  const float* wc1  = (const float*)d_in[3];
  const float* bc1  = (const float*)d_in[4];
  const float* wc2  = (const float*)d_in[5];
  const float* bc2  = (const float*)d_in[6];
  const float* wd1  = (const float*)d_in[7];
  const float* bd1  = (const float*)d_in[8];
  const float* wd2  = (const float*)d_in[9];
  const float* bd2  = (const float*)d_in[10];
  const float* fc2w = (const float*)d_in[11];
  const float* fc2b = (const float*)d_in[12];
  const float* attw = (const float*)d_in[13];
  const int*   ei   = (const int*)d_in[14];
  float* out = (float*)d_out;
  char* ws = (char*)d_ws;

  constexpr size_t BUFB = (size_t)NG * NN * NFEAT * 2;   // 38,400,000 B
  u16* WT   = (u16*)(ws + 0);
  u16* buf0 = (u16*)(ws + 327680);                        // pre_feat -> own2
  u16* buf1 = (u16*)(ws + 327680 + 1 * BUFB);             // conv1_f -> oth1 -> oth2
  u16* buf2 = (u16*)(ws + 327680 + 2 * BUFB);             // enc
  u16* bufT = (u16*)(ws + 327680 + 3 * BUFB);             // enc-agg tmp -> own1
  u16* bufF = (u16*)(ws + 327680 + 4 * BUFB);             // fused 512B rows (2*BUFB), later each_fin
  size_t off = 327680 + 6 * BUFB;
  u16* encsum = (u16*)(ws + off); off += (size_t)NN * NFEAT * 2;
  float* dinv = (float*)(ws + off); off += (size_t)NG * NN * 4;
  int* rowptr = (int*)(ws + off); off += 600064;
  int* colbuf = (int*)(ws + off); off += (size_t)NG * NE * 4;
  size_t zero_off = off;
  int* deg     = (int*)(ws + off); off += (size_t)NG * NN * 4;
  int* cursor  = (int*)(ws + off); off += (size_t)NG * NN * 4;
  float* colsum = (float*)(ws + off); off += 1536;
  float* slots  = (float*)(ws + off); off += 64;
  size_t zero_bytes = off - zero_off;
  float* uvec = (float*)(ws + off); off += 1536;
  if (ws_size < off) return;   // workspace too small: fail loudly without OOB writes

  hipMemsetAsync(ws + zero_off, 0, zero_bytes, stream);

  wprep_kernel<<<576, 256, 0, stream>>>(fc1w, wc1, wc2, wd1, wd2, fc2w, WT);
  deg_kernel<<<7032, 256, 0, stream>>>(ei, deg);
  scan_kernel<<<NG, 1024, 0, stream>>>(deg, rowptr, dinv);
  fill_kernel<<<7032, 256, 0, stream>>>(ei, rowptr, cursor, colbuf);

  const u16* WT_fc1 = WT;
  const u16* WT_c1  = WT + 49152;
  const u16* WT_c2  = WT + 65536;
  const u16* WT_d1  = WT + 81920;
  const u16* WT_d2  = WT + 98304;
  const u16* WT_f2a = WT + 114688;
  const u16* WT_f2b = WT + 131072;
  dim3 gg(391, NG), ag(12500, NG);

  // pre_feat = x @ fc1_w + fc1_b                      -> buf0
  gemm_kernel<1><<<gg, 256, 0, stream>>>(x, nullptr, WT_fc1, nullptr, fc1b, buf0, nullptr, 1, 1, 1, 128, 0, 1);
  // conv1_f = GCN(pre_feat, wc1, bc1)                 -> buf1
  gemm_kernel<0><<<gg, 256, 0, stream>>>(buf0, nullptr, WT_c1, nullptr, nullptr, bufT, dinv, 0, 0, 0, 128, 0, 1);
  agg_kernel<<<ag, 256, 0, stream>>>(bufT, buf1, bc1, dinv, rowptr, colbuf);
  // enc = GCN(conv1_f, wc2, bc2)                      -> buf2
  gemm_kernel<0><<<gg, 256, 0, stream>>>(buf1, nullptr, WT_c2, nullptr, nullptr, bufT, dinv, 0, 0, 0, 128, 0, 1);
  agg_kernel<<<ag, 256, 0, stream>>>(bufT, buf2, bc2, dinv, rowptr, colbuf);
  // enc_sum / used_feat / colsum ; global_vec -> u
  encsum_kernel<<<256, 256, 0, stream>>>(buf2, encsum, out + 6400000, colsum);
  gvecu_kernel<<<1, 128, 0, stream>>>(colsum, attw, uvec);
  // decoder layer 1 (fused): F = [enc@Wd1 | encsum@Wd1], both dinv-scaled
  gemm_kernel<0><<<gg, 256, 0, stream>>>(buf2, nullptr, WT_d1, nullptr, nullptr, bufF, dinv, 0, 0, 0, 256, 0, 1);
  gemm_kernel<0><<<gg, 256, 0, stream>>>(encsum, nullptr, WT_d1, nullptr, nullptr, bufF, dinv, 0, 0, 0, 256, 128, 0);
  //   own1 -> bufT, oth1 = (T-U)/2 -> buf1 (conv1_f consumed as SQ ref here)
  agg2_kernel<1, true><<<ag, 256, 0, stream>>>(bufF, bufT, buf1, bd1, dinv, rowptr, colbuf, buf1, slots + 0);
  // decoder layer 2 (fused): F = [own1@Wd2 | oth1@Wd2], both dinv-scaled
  gemm_kernel<0><<<gg, 256, 0, stream>>>(bufT, nullptr, WT_d2, nullptr, nullptr, bufF, dinv, 0, 0, 0, 256, 0, 1);
  gemm_kernel<0><<<gg, 256, 0, stream>>>(buf1, nullptr, WT_d2, nullptr, nullptr, bufF, dinv, 0, 0, 0, 256, 128, 1);
  //   own2 -> buf0 (pre_feat consumed as SQ ref here), oth2 -> buf1
  agg2_kernel<0, true><<<ag, 256, 0, stream>>>(bufF, buf0, buf1, bd2, dinv, rowptr, colbuf, buf0, slots + 3);
  // each_fin = [own2|oth2] @ fc2_w + fc2_b            -> bufF (first half)
  gemm_kernel<3><<<gg, 256, 0, stream>>>(buf0, buf1, WT_f2a, WT_f2b, fc2b, bufF, nullptr, 0, 0, 1, 128, 0, 1);
  // fuse_feat + obf0 pair sums
  fuse_kernel<<<256, 256, 0, stream>>>(bufF, out, slots);
  // comp_re
  comp_kernel<<<12500, 256, 0, stream>>>(buf2, uvec, out + 12800000);
  final_kernel<<<1, 64, 0, stream>>>(slots, out);
}